// Round 3
// baseline (1031.937 us; speedup 1.0000x reference)
//
#include <hip/hip_runtime.h>

typedef float    f32x4  __attribute__((ext_vector_type(4)));
typedef __bf16   bf16x8 __attribute__((ext_vector_type(8)));
typedef unsigned short us4 __attribute__((ext_vector_type(4)));
typedef unsigned short us8 __attribute__((ext_vector_type(8)));

#define NGRAPHS 2048
#define K1DIM 144
#define K1PAD 160
#define NREP  32    // bn partial-sum replicas

static __device__ __forceinline__ unsigned short f2bf(float f) {
    __bf16 h = (__bf16)f;
    return __builtin_bit_cast(unsigned short, h);
}
static __device__ __forceinline__ float bf2f(unsigned short u) {
    __bf16 h = __builtin_bit_cast(__bf16, u);
    return (float)h;
}

// ---------------- K0: segment boundaries via binary search (batch sorted) ------
__global__ void k_bounds(const int* __restrict__ batch, int* __restrict__ start, int N) {
    int g = blockIdx.x * blockDim.x + threadIdx.x;
    if (g > NGRAPHS) return;
    if (g == NGRAPHS) { start[g] = N; return; }
    int lo = 0, hi = N;
    while (lo < hi) {
        int mid = (lo + hi) >> 1;
        if (batch[mid] < g) lo = mid + 1; else hi = mid;
    }
    start[g] = lo;
}

// ---------------- K1: weights -> bf16 (W1 padded K 144->160 with zeros) ---------
__global__ void k_prep(const float* __restrict__ g1w, const float* __restrict__ g2w,
                       unsigned short* __restrict__ W1, unsigned short* __restrict__ W2) {
    int n = blockIdx.x;      // 0..127
    int t = threadIdx.x;     // 0..191
    if (t < K1PAD) W1[n * K1PAD + t] = (t < K1DIM) ? f2bf(g1w[n * K1DIM + t]) : (unsigned short)0;
    if (t < 128)   W2[n * 128 + t]   = f2bf(g2w[n * 128 + t]);
}

// ---------------- K2: segment sums of x0 = concat(x, pers), one block/graph ----
__global__ __launch_bounds__(256) void k_seg1(
        const float* __restrict__ x, const float* __restrict__ pers,
        const int* __restrict__ start, float* __restrict__ sum1,
        float* __restrict__ cnt, int N) {
    __shared__ f32x4 red[7][36];
    int g = blockIdx.x;
    int s = start[g], e = start[g + 1];
    int tid = threadIdx.x;
    int cg = tid % 36, rs = tid / 36;   // rs 0..7; rs==7 idle
    f32x4 acc = {0.f, 0.f, 0.f, 0.f};
    if (rs < 7) {
        if (cg < 32) {
            for (int r = s + rs; r < e; r += 7) {
                f32x4 v = *(const f32x4*)(x + (size_t)r * 128 + cg * 4);
                acc += v;
            }
        } else {
            int j = cg - 32;
            const float* p0 = pers + (size_t)(2 * j)     * 2 * (size_t)N;
            const float* p1 = pers + (size_t)(2 * j + 1) * 2 * (size_t)N;
            for (int r = s + rs; r < e; r += 7) {
                float2 a = *(const float2*)(p0 + (size_t)r * 2);
                float2 b = *(const float2*)(p1 + (size_t)r * 2);
                acc[0] += a.x; acc[1] += a.y; acc[2] += b.x; acc[3] += b.y;
            }
        }
        red[rs][cg] = acc;
    }
    __syncthreads();
    if (tid < 36) {
        f32x4 t = red[0][tid];
        #pragma unroll
        for (int k = 1; k < 7; ++k) t += red[k][tid];
        *(f32x4*)(sum1 + (size_t)g * K1DIM + tid * 4) = t;
    }
    if (tid == 0) cnt[g] = (float)(e - s);
}

// ---------------- K3/K6: c[g][n] = gb[n] - (sum[g]/max(cnt,1)) . lw[n] ----------
__global__ void k_corr(const float* __restrict__ sums, const float* __restrict__ cnt,
                       const float* __restrict__ lw, const float* __restrict__ gb,
                       float* __restrict__ cp, int K) {
    int g = blockIdx.x, n = threadIdx.x;
    float inv = 1.f / fmaxf(cnt[g], 1.f);
    const float* srow = sums + (size_t)g * K;
    const float* wrow = lw   + (size_t)n * K;
    float acc = 0.f;
    for (int k = 0; k < K; ++k) acc += srow[k] * wrow[k];
    cp[(size_t)g * 128 + n] = gb[n] - acc * inv;
}

// ---------------- K4: GEMM1 (x0 @ g1w.T) + c1[seg] + ReLU -> x1 (bf16)
//                 + fused segment-sum of x1 into sum2 --------------------------
// SWAPPED-OPERAND mfma: D[feature][x_row] so each lane owns ONE x-row
// (tileBase+m) and features nt*16+quad*4+r. Epilogue: 1 batch load, 8 float4
// c-loads, 8x8B packed stores per lane (vs 4/32/32-scalar before).
__global__ __launch_bounds__(256, 4) void k_gemm1(
        const float* __restrict__ x, const float* __restrict__ pers,
        const int* __restrict__ batch, const unsigned short* __restrict__ W1,
        const float* __restrict__ c1p, unsigned short* __restrict__ x1,
        float* __restrict__ sum2, int N) {
    int tid  = threadIdx.x;
    int wave = tid >> 6, lane = tid & 63;
    int m = lane & 15, quad = lane >> 4;
    long tileBase = (long)blockIdx.x * 64 + wave * 16;   // 16 rows per wave
    if (tileBase >= N) return;

    long arow = tileBase + m;
    bool ok = (arow < N);
    if (!ok) arow = (long)N - 1;                         // clamp for loads
    const float* xr = x + (size_t)arow * 128;

    // ---- x-row fragments (B-operand of swapped mfma): k = kb*32 + quad*8 + j --
    bf16x8 a[5];
    #pragma unroll
    for (int kb = 0; kb < 4; ++kb) {
        float4 u0 = *(const float4*)(xr + kb * 32 + quad * 8);
        float4 u1 = *(const float4*)(xr + kb * 32 + quad * 8 + 4);
        bf16x8 t;
        t[0] = (__bf16)u0.x; t[1] = (__bf16)u0.y; t[2] = (__bf16)u0.z; t[3] = (__bf16)u0.w;
        t[4] = (__bf16)u1.x; t[5] = (__bf16)u1.y; t[6] = (__bf16)u1.z; t[7] = (__bf16)u1.w;
        a[kb] = t;
    }
    {
        bf16x8 t;
        #pragma unroll
        for (int j = 0; j < 8; ++j) t[j] = (__bf16)0.f;
        if (quad < 2) {
            #pragma unroll
            for (int pp = 0; pp < 4; ++pp) {
                int p = quad * 4 + pp;
                float2 v = *(const float2*)(pers + (size_t)p * 2 * (size_t)N + (size_t)arow * 2);
                t[pp * 2]     = (__bf16)v.x;
                t[pp * 2 + 1] = (__bf16)v.y;
            }
        }
        a[4] = t;
    }

    // ---- MFMA (swapped): acc[nt][r] = out[feature nt*16+quad*4+r][row tileBase+m]
    f32x4 acc[8];
    #pragma unroll
    for (int nt = 0; nt < 8; ++nt) acc[nt] = (f32x4){0.f, 0.f, 0.f, 0.f};

    #pragma unroll
    for (int kb = 0; kb < 5; ++kb) {
        #pragma unroll
        for (int nt = 0; nt < 8; ++nt) {
            bf16x8 b = *(const bf16x8*)(W1 + (size_t)(nt * 16 + m) * K1PAD + kb * 32 + quad * 8);
            acc[nt] = __builtin_amdgcn_mfma_f32_16x16x32_bf16(b, a[kb], acc[nt], 0, 0, 0);
        }
    }

    // ---- epilogue: one row per lane; relu + c1; packed 8B stores -------------
    int seg = batch[arow];
    const float* crow = c1p + (size_t)seg * 128;
    #pragma unroll
    for (int nt = 0; nt < 8; ++nt) {
        float4 c = *(const float4*)(crow + nt * 16 + quad * 4);
        f32x4 v;
        v[0] = fmaxf(acc[nt][0] + c.x, 0.f);
        v[1] = fmaxf(acc[nt][1] + c.y, 0.f);
        v[2] = fmaxf(acc[nt][2] + c.z, 0.f);
        v[3] = fmaxf(acc[nt][3] + c.w, 0.f);
        if (!ok) v = (f32x4){0.f, 0.f, 0.f, 0.f};
        acc[nt] = v;
        if (ok) {
            us4 o;
            o[0] = f2bf(v[0]); o[1] = f2bf(v[1]); o[2] = f2bf(v[2]); o[3] = f2bf(v[3]);
            *(us4*)(x1 + (size_t)arow * 128 + nt * 16 + quad * 4) = o;
        }
    }

    // ---- fused segment-sum of relu'd tile: reduce across m-lanes -------------
    long lastRow = tileBase + 15; if (lastRow > (long)N - 1) lastRow = (long)N - 1;
    int sLo = batch[tileBase];
    int sHi = batch[lastRow];
    if (sLo == sHi) {
        #pragma unroll
        for (int nt = 0; nt < 8; ++nt) {
            #pragma unroll
            for (int r = 0; r < 4; ++r) {
                float p = acc[nt][r];
                p += __shfl_xor(p, 1); p += __shfl_xor(p, 2);
                p += __shfl_xor(p, 4); p += __shfl_xor(p, 8);
                if (m == 0) atomicAdd(&sum2[(size_t)sLo * 128 + nt * 16 + quad * 4 + r], p);
            }
        }
    } else {
        for (int sg = sLo; sg <= sHi; ++sg) {
            bool mine = ok && (seg == sg);
            #pragma unroll
            for (int nt = 0; nt < 8; ++nt) {
                #pragma unroll
                for (int r = 0; r < 4; ++r) {
                    float p = mine ? acc[nt][r] : 0.f;
                    p += __shfl_xor(p, 1); p += __shfl_xor(p, 2);
                    p += __shfl_xor(p, 4); p += __shfl_xor(p, 8);
                    if (m == 0) atomicAdd(&sum2[(size_t)sg * 128 + nt * 16 + quad * 4 + r], p);
                }
            }
        }
    }
}

// ---------------- K7: GEMM2 + c2[seg] -> x2 (bf16 or f32) + BN partials --------
// Swapped-operand layout: lane owns rows waveBase+t*16+m (t=0,1), features
// nt*16+quad*4+r. acc overwritten with masked post-c2 values for BN reduce.
__global__ __launch_bounds__(256, 4) void k_gemm2(
        const unsigned short* __restrict__ x1, const int* __restrict__ batch,
        const unsigned short* __restrict__ W2, const float* __restrict__ c2p,
        float* __restrict__ x2f, unsigned short* __restrict__ x2b, int mode,
        float* __restrict__ bnp, int N) {
    __shared__ float lsum[128], lsq[128];
    int tid = threadIdx.x;
    if (tid < 128) { lsum[tid] = 0.f; lsq[tid] = 0.f; }
    __syncthreads();

    int wave = tid >> 6, lane = tid & 63;
    int m = lane & 15, quad = lane >> 4;
    long waveBase = (long)blockIdx.x * 128 + wave * 32;

    bf16x8 a[2][4];
    #pragma unroll
    for (int t = 0; t < 2; ++t) {
        long ra = waveBase + t * 16 + m;
        if (ra > (long)N - 1) ra = (long)N - 1;   // clamp; masked in epilogue
        #pragma unroll
        for (int kb = 0; kb < 4; ++kb)
            a[t][kb] = *(const bf16x8*)(x1 + (size_t)ra * 128 + kb * 32 + quad * 8);
    }

    f32x4 acc[2][8];
    #pragma unroll
    for (int t = 0; t < 2; ++t)
        #pragma unroll
        for (int nt = 0; nt < 8; ++nt) acc[t][nt] = (f32x4){0.f, 0.f, 0.f, 0.f};

    #pragma unroll
    for (int nt = 0; nt < 8; ++nt) {
        #pragma unroll
        for (int kb = 0; kb < 4; ++kb) {
            bf16x8 b = *(const bf16x8*)(W2 + (size_t)(nt * 16 + m) * 128 + kb * 32 + quad * 8);
            acc[0][nt] = __builtin_amdgcn_mfma_f32_16x16x32_bf16(b, a[0][kb], acc[0][nt], 0, 0, 0);
            acc[1][nt] = __builtin_amdgcn_mfma_f32_16x16x32_bf16(b, a[1][kb], acc[1][nt], 0, 0, 0);
        }
    }

    // epilogue: per row-tile t, lane owns row waveBase+t*16+m
    #pragma unroll
    for (int t = 0; t < 2; ++t) {
        long grow = waveBase + t * 16 + m;
        bool ok = (grow < N);
        long gr = ok ? grow : (long)N - 1;
        int seg = batch[gr];
        const float* crow = c2p + (size_t)seg * 128;
        #pragma unroll
        for (int nt = 0; nt < 8; ++nt) {
            float4 c = *(const float4*)(crow + nt * 16 + quad * 4);
            f32x4 v;
            v[0] = acc[t][nt][0] + c.x;
            v[1] = acc[t][nt][1] + c.y;
            v[2] = acc[t][nt][2] + c.z;
            v[3] = acc[t][nt][3] + c.w;
            if (!ok) v = (f32x4){0.f, 0.f, 0.f, 0.f};
            acc[t][nt] = v;            // reuse as BN source (zeroed when invalid)
            if (ok) {
                if (mode) {
                    us4 o;
                    o[0] = f2bf(v[0]); o[1] = f2bf(v[1]); o[2] = f2bf(v[2]); o[3] = f2bf(v[3]);
                    *(us4*)(x2b + (size_t)grow * 128 + nt * 16 + quad * 4) = o;
                } else {
                    *(float4*)(x2f + (size_t)grow * 128 + nt * 16 + quad * 4) =
                        (float4){v[0], v[1], v[2], v[3]};
                }
            }
        }
    }

    // BN partials: reduce sum & sq across the 16 m-lanes per feature
    #pragma unroll
    for (int nt = 0; nt < 8; ++nt) {
        #pragma unroll
        for (int r = 0; r < 4; ++r) {
            float s = acc[0][nt][r] + acc[1][nt][r];
            float q = acc[0][nt][r] * acc[0][nt][r] + acc[1][nt][r] * acc[1][nt][r];
            s += __shfl_xor(s, 1); s += __shfl_xor(s, 2);
            s += __shfl_xor(s, 4); s += __shfl_xor(s, 8);
            q += __shfl_xor(q, 1); q += __shfl_xor(q, 2);
            q += __shfl_xor(q, 4); q += __shfl_xor(q, 8);
            if (m == 0) {
                int f = nt * 16 + quad * 4 + r;
                atomicAdd(&lsum[f], s);
                atomicAdd(&lsq[f], q);
            }
        }
    }
    __syncthreads();
    if (tid < 128) {
        int rep = (int)(blockIdx.x & (NREP - 1));
        atomicAdd(&bnp[rep * 256 + tid],       lsum[tid]);
        atomicAdd(&bnp[rep * 256 + 128 + tid], lsq[tid]);
    }
}

// ---------------- K8: BN finalize -> scale/shift -------------------------------
__global__ void k_bnfin(const float* __restrict__ bnp, const float* __restrict__ bn_g,
                        const float* __restrict__ bn_b, float* __restrict__ bnscale,
                        float* __restrict__ bnshift, int N) {
    int t = threadIdx.x;   // 128
    float s = 0.f, q = 0.f;
    for (int rep = 0; rep < NREP; ++rep) {
        s += bnp[rep * 256 + t];
        q += bnp[rep * 256 + 128 + t];
    }
    float invN = 1.f / (float)N;
    float mu  = s * invN;
    float var = fmaxf(q * invN - mu * mu, 0.f);
    float sc  = bn_g[t] * rsqrtf(var + 1e-5f);
    bnscale[t] = sc;
    bnshift[t] = bn_b[t] - mu * sc;
}

// ---------------- K9: out = x + x2*scale + shift -------------------------------
__global__ void k_final(const float* __restrict__ x, const unsigned short* __restrict__ x2b,
                        const float* __restrict__ x2f, int mode,
                        const float* __restrict__ bnscale, const float* __restrict__ bnshift,
                        float* __restrict__ out, long nThreads) {
    long i = (long)blockIdx.x * blockDim.x + threadIdx.x;
    if (i >= nThreads) return;
    long base = i * 8;
    int n0 = (int)(base & 127);
    float4 sc0 = *(const float4*)(bnscale + n0);
    float4 sc1 = *(const float4*)(bnscale + n0 + 4);
    float4 sh0 = *(const float4*)(bnshift + n0);
    float4 sh1 = *(const float4*)(bnshift + n0 + 4);
    float4 xa = *(const float4*)(x + base);
    float4 xb = *(const float4*)(x + base + 4);
    float v[8];
    if (mode) {
        us8 u = *(const us8*)(x2b + base);
        #pragma unroll
        for (int j = 0; j < 8; ++j) v[j] = bf2f(u[j]);
    } else {
        float4 va = *(const float4*)(x2f + base);
        float4 vb = *(const float4*)(x2f + base + 4);
        v[0] = va.x; v[1] = va.y; v[2] = va.z; v[3] = va.w;
        v[4] = vb.x; v[5] = vb.y; v[6] = vb.z; v[7] = vb.w;
    }
    float4 oa, ob;
    oa.x = xa.x + v[0] * sc0.x + sh0.x;
    oa.y = xa.y + v[1] * sc0.y + sh0.y;
    oa.z = xa.z + v[2] * sc0.z + sh0.z;
    oa.w = xa.w + v[3] * sc0.w + sh0.w;
    ob.x = xb.x + v[4] * sc1.x + sh1.x;
    ob.y = xb.y + v[5] * sc1.y + sh1.y;
    ob.z = xb.z + v[6] * sc1.z + sh1.z;
    ob.w = xb.w + v[7] * sc1.w + sh1.w;
    *(float4*)(out + base)     = oa;
    *(float4*)(out + base + 4) = ob;
}

extern "C" void kernel_launch(void* const* d_in, const int* in_sizes, int n_in,
                              void* d_out, int out_size, void* d_ws, size_t ws_size,
                              hipStream_t stream) {
    const float* x    = (const float*)d_in[0];
    const int*   bat  = (const int*)  d_in[1];
    const float* pers = (const float*)d_in[2];
    const float* g1w  = (const float*)d_in[3];
    const float* g1b  = (const float*)d_in[4];
    const float* l1w  = (const float*)d_in[5];
    const float* g2w  = (const float*)d_in[6];
    const float* g2b  = (const float*)d_in[7];
    const float* l2w  = (const float*)d_in[8];
    const float* bng  = (const float*)d_in[9];
    const float* bnb  = (const float*)d_in[10];
    int N = in_sizes[1];                 // 500000
    float* out = (float*)d_out;

    // ws layout: zeroed region first (sum2 + bnp only)
    char* ws = (char*)d_ws;
    float* sum2 = (float*)(ws + 0);                       // 2048*128*4 = 1048576
    float* bnp  = (float*)(ws + 1048576);                 // 32*256*4   = 32768
    size_t zero_bytes = 1081344;
    int*   start = (int*)(ws + 1081344);                  // 2049*4 -> pad 8704
    float* cnt  = (float*)(ws + 1090048);                 // 2048*4     = 8192
    float* sum1 = (float*)(ws + 1098240);                 // 2048*144*4 = 1179648
    float* c1p  = (float*)(ws + 2277888);                 // 1048576
    float* c2p  = (float*)(ws + 3326464);                 // 1048576
    unsigned short* W1 = (unsigned short*)(ws + 4375040); // 128*160*2 = 40960
    unsigned short* W2 = (unsigned short*)(ws + 4416000); // 128*128*2 = 32768
    float* bnscale = (float*)(ws + 4448768);              // 512
    float* bnshift = (float*)(ws + 4449280);              // 512
    unsigned short* x1 = (unsigned short*)(ws + 4449792); // N*128*2 = 128000000
    unsigned short* x2b = (unsigned short*)(ws + 132449792); // N*128*2 = 128000000
    size_t need_bf16 = 132449792 + (size_t)N * 128 * 2;
    int mode = (ws_size >= need_bf16) ? 1 : 0;

    hipMemsetAsync(ws, 0, zero_bytes, stream);

    int gridRows64  = (N + 63) / 64;
    int gridRows128 = (N + 127) / 128;

    k_bounds<<<(NGRAPHS + 256) / 256 + 1, 256, 0, stream>>>(bat, start, N);
    k_prep <<<128, 192, 0, stream>>>(g1w, g2w, W1, W2);
    k_seg1 <<<NGRAPHS, 256, 0, stream>>>(x, pers, start, sum1, cnt, N);
    k_corr <<<NGRAPHS, 128, 0, stream>>>(sum1, cnt, l1w, g1b, c1p, K1DIM);
    k_gemm1<<<gridRows64, 256, 0, stream>>>(x, pers, bat, W1, c1p, x1, sum2, N);
    k_corr <<<NGRAPHS, 128, 0, stream>>>(sum2, cnt, l2w, g2b, c2p, 128);
    k_gemm2<<<gridRows128, 256, 0, stream>>>(x1, bat, W2, c2p, out, x2b, mode, bnp, N);
    k_bnfin<<<1, 128, 0, stream>>>(bnp, bng, bnb, bnscale, bnshift, N);
    long nThreads = ((long)N * 128) / 8;
    k_final<<<(int)((nThreads + 255) / 256), 256, 0, stream>>>(x, x2b, out, mode,
                                                               bnscale, bnshift, out, nThreads);
}

// Round 4
// 1007.134 us; speedup vs baseline: 1.0246x; 1.0246x over previous
//
#include <hip/hip_runtime.h>

typedef float    f32x4  __attribute__((ext_vector_type(4)));
typedef __bf16   bf16x8 __attribute__((ext_vector_type(8)));
typedef unsigned short us4 __attribute__((ext_vector_type(4)));
typedef unsigned short us8 __attribute__((ext_vector_type(8)));

#define NGRAPHS 2048
#define K1DIM 144
#define K1PAD 160
#define NREP  32    // bn partial-sum replicas

static __device__ __forceinline__ unsigned short f2bf(float f) {
    __bf16 h = (__bf16)f;
    return __builtin_bit_cast(unsigned short, h);
}
static __device__ __forceinline__ float bf2f(unsigned short u) {
    __bf16 h = __builtin_bit_cast(__bf16, u);
    return (float)h;
}

// ---------------- K0: segment boundaries via binary search (batch sorted) ------
__global__ void k_bounds(const int* __restrict__ batch, int* __restrict__ start, int N) {
    int g = blockIdx.x * blockDim.x + threadIdx.x;
    if (g > NGRAPHS) return;
    if (g == NGRAPHS) { start[g] = N; return; }
    int lo = 0, hi = N;
    while (lo < hi) {
        int mid = (lo + hi) >> 1;
        if (batch[mid] < g) lo = mid + 1; else hi = mid;
    }
    start[g] = lo;
}

// ---------------- K1: weights -> bf16 (W1 padded K 144->160 with zeros) ---------
__global__ void k_prep(const float* __restrict__ g1w, const float* __restrict__ g2w,
                       unsigned short* __restrict__ W1, unsigned short* __restrict__ W2) {
    int n = blockIdx.x;      // 0..127
    int t = threadIdx.x;     // 0..191
    if (t < K1PAD) W1[n * K1PAD + t] = (t < K1DIM) ? f2bf(g1w[n * K1DIM + t]) : (unsigned short)0;
    if (t < 128)   W2[n * 128 + t]   = f2bf(g2w[n * 128 + t]);
}

// ---------------- K2: segment sums of x0 = concat(x, pers), one block/graph ----
__global__ __launch_bounds__(256) void k_seg1(
        const float* __restrict__ x, const float* __restrict__ pers,
        const int* __restrict__ start, float* __restrict__ sum1,
        float* __restrict__ cnt, int N) {
    __shared__ f32x4 red[7][36];
    int g = blockIdx.x;
    int s = start[g], e = start[g + 1];
    int tid = threadIdx.x;
    int cg = tid % 36, rs = tid / 36;   // rs 0..7; rs==7 idle
    f32x4 acc = {0.f, 0.f, 0.f, 0.f};
    if (rs < 7) {
        if (cg < 32) {
            for (int r = s + rs; r < e; r += 7) {
                f32x4 v = *(const f32x4*)(x + (size_t)r * 128 + cg * 4);
                acc += v;
            }
        } else {
            int j = cg - 32;
            const float* p0 = pers + (size_t)(2 * j)     * 2 * (size_t)N;
            const float* p1 = pers + (size_t)(2 * j + 1) * 2 * (size_t)N;
            for (int r = s + rs; r < e; r += 7) {
                float2 a = *(const float2*)(p0 + (size_t)r * 2);
                float2 b = *(const float2*)(p1 + (size_t)r * 2);
                acc[0] += a.x; acc[1] += a.y; acc[2] += b.x; acc[3] += b.y;
            }
        }
        red[rs][cg] = acc;
    }
    __syncthreads();
    if (tid < 36) {
        f32x4 t = red[0][tid];
        #pragma unroll
        for (int k = 1; k < 7; ++k) t += red[k][tid];
        *(f32x4*)(sum1 + (size_t)g * K1DIM + tid * 4) = t;
    }
    if (tid == 0) cnt[g] = (float)(e - s);
}

// ---------------- K3/K6: c[g][n] = gb[n] - (sum[g]/max(cnt,1)) . lw[n] ----------
__global__ void k_corr(const float* __restrict__ sums, const float* __restrict__ cnt,
                       const float* __restrict__ lw, const float* __restrict__ gb,
                       float* __restrict__ cp, int K) {
    int g = blockIdx.x, n = threadIdx.x;
    float inv = 1.f / fmaxf(cnt[g], 1.f);
    const float* srow = sums + (size_t)g * K;
    const float* wrow = lw   + (size_t)n * K;
    float acc = 0.f;
    for (int k = 0; k < K; ++k) acc += srow[k] * wrow[k];
    cp[(size_t)g * 128 + n] = gb[n] - acc * inv;
}

// ---------------- K4: GEMM1 (x0 @ g1w.T) + c1[seg] + ReLU -> x1 (bf16)
//                 + fused segment-sum of x1 into sum2 --------------------------
// Swapped-operand mfma; 32 rows/wave (2 sub-tiles sharing every W1 B-frag);
// seg prefetched at entry so the c1p gather latency hides under MFMA work.
__global__ __launch_bounds__(256, 3) void k_gemm1(
        const float* __restrict__ x, const float* __restrict__ pers,
        const int* __restrict__ batch, const unsigned short* __restrict__ W1,
        const float* __restrict__ c1p, unsigned short* __restrict__ x1,
        float* __restrict__ sum2, int N) {
    int tid  = threadIdx.x;
    int wave = tid >> 6, lane = tid & 63;
    int m = lane & 15, quad = lane >> 4;
    long tileBase = (long)blockIdx.x * 128 + wave * 32;   // 32 rows per wave
    if (tileBase >= N) return;

    long row[2]; bool ok[2]; int seg[2];
    #pragma unroll
    for (int t = 0; t < 2; ++t) {
        long r = tileBase + t * 16 + m;
        ok[t]  = (r < N);
        row[t] = ok[t] ? r : (long)N - 1;     // clamp; masked in epilogue
        seg[t] = batch[row[t]];               // EARLY issue: hides c1p chase
    }

    // ---- x-row fragments: k = kb*32 + quad*8 + j ----
    bf16x8 a[2][5];
    #pragma unroll
    for (int t = 0; t < 2; ++t) {
        const float* xr = x + (size_t)row[t] * 128;
        #pragma unroll
        for (int kb = 0; kb < 4; ++kb) {
            float4 u0 = *(const float4*)(xr + kb * 32 + quad * 8);
            float4 u1 = *(const float4*)(xr + kb * 32 + quad * 8 + 4);
            bf16x8 w;
            w[0] = (__bf16)u0.x; w[1] = (__bf16)u0.y; w[2] = (__bf16)u0.z; w[3] = (__bf16)u0.w;
            w[4] = (__bf16)u1.x; w[5] = (__bf16)u1.y; w[6] = (__bf16)u1.z; w[7] = (__bf16)u1.w;
            a[t][kb] = w;
        }
        bf16x8 w;
        #pragma unroll
        for (int j = 0; j < 8; ++j) w[j] = (__bf16)0.f;
        if (quad < 2) {
            #pragma unroll
            for (int pp = 0; pp < 4; ++pp) {
                int p = quad * 4 + pp;
                float2 v = *(const float2*)(pers + (size_t)p * 2 * (size_t)N + (size_t)row[t] * 2);
                w[pp * 2]     = (__bf16)v.x;
                w[pp * 2 + 1] = (__bf16)v.y;
            }
        }
        a[t][4] = w;
    }

    // ---- MFMA: each W1 B-frag feeds BOTH sub-tiles ----
    f32x4 acc[2][8];
    #pragma unroll
    for (int t = 0; t < 2; ++t)
        #pragma unroll
        for (int nt = 0; nt < 8; ++nt) acc[t][nt] = (f32x4){0.f, 0.f, 0.f, 0.f};

    #pragma unroll
    for (int kb = 0; kb < 5; ++kb) {
        #pragma unroll
        for (int nt = 0; nt < 8; ++nt) {
            bf16x8 b = *(const bf16x8*)(W1 + (size_t)(nt * 16 + m) * K1PAD + kb * 32 + quad * 8);
            acc[0][nt] = __builtin_amdgcn_mfma_f32_16x16x32_bf16(b, a[0][kb], acc[0][nt], 0, 0, 0);
            acc[1][nt] = __builtin_amdgcn_mfma_f32_16x16x32_bf16(b, a[1][kb], acc[1][nt], 0, 0, 0);
        }
    }

    // ---- epilogue: lane owns rows row[0], row[1]; relu + c1; packed 8B stores --
    #pragma unroll
    for (int t = 0; t < 2; ++t) {
        const float* crow = c1p + (size_t)seg[t] * 128;
        #pragma unroll
        for (int nt = 0; nt < 8; ++nt) {
            float4 c = *(const float4*)(crow + nt * 16 + quad * 4);
            f32x4 v;
            v[0] = fmaxf(acc[t][nt][0] + c.x, 0.f);
            v[1] = fmaxf(acc[t][nt][1] + c.y, 0.f);
            v[2] = fmaxf(acc[t][nt][2] + c.z, 0.f);
            v[3] = fmaxf(acc[t][nt][3] + c.w, 0.f);
            if (!ok[t]) v = (f32x4){0.f, 0.f, 0.f, 0.f};
            acc[t][nt] = v;
            if (ok[t]) {
                us4 o;
                o[0] = f2bf(v[0]); o[1] = f2bf(v[1]); o[2] = f2bf(v[2]); o[3] = f2bf(v[3]);
                *(us4*)(x1 + (size_t)row[t] * 128 + nt * 16 + quad * 4) = o;
            }
        }
    }

    // ---- fused segment-sum across 32 rows: reduce over m-lanes ---------------
    long lastRow = tileBase + 31; if (lastRow > (long)N - 1) lastRow = (long)N - 1;
    int sLo = batch[tileBase];
    int sHi = batch[lastRow];
    if (sLo == sHi) {
        #pragma unroll
        for (int nt = 0; nt < 8; ++nt) {
            #pragma unroll
            for (int r = 0; r < 4; ++r) {
                float p = acc[0][nt][r] + acc[1][nt][r];
                p += __shfl_xor(p, 1); p += __shfl_xor(p, 2);
                p += __shfl_xor(p, 4); p += __shfl_xor(p, 8);
                if (m == 0) atomicAdd(&sum2[(size_t)sLo * 128 + nt * 16 + quad * 4 + r], p);
            }
        }
    } else {
        for (int sg = sLo; sg <= sHi; ++sg) {
            bool m0 = (seg[0] == sg), m1 = (seg[1] == sg);
            #pragma unroll
            for (int nt = 0; nt < 8; ++nt) {
                #pragma unroll
                for (int r = 0; r < 4; ++r) {
                    float p = (m0 ? acc[0][nt][r] : 0.f) + (m1 ? acc[1][nt][r] : 0.f);
                    p += __shfl_xor(p, 1); p += __shfl_xor(p, 2);
                    p += __shfl_xor(p, 4); p += __shfl_xor(p, 8);
                    if (m == 0) atomicAdd(&sum2[(size_t)sg * 128 + nt * 16 + quad * 4 + r], p);
                }
            }
        }
    }
}

// ---------------- K7: GEMM2 + c2[seg] -> x2 (bf16 or f32) + BN partials --------
// Swapped-operand layout; seg prefetched at entry.
__global__ __launch_bounds__(256, 4) void k_gemm2(
        const unsigned short* __restrict__ x1, const int* __restrict__ batch,
        const unsigned short* __restrict__ W2, const float* __restrict__ c2p,
        float* __restrict__ x2f, unsigned short* __restrict__ x2b, int mode,
        float* __restrict__ bnp, int N) {
    __shared__ float lsum[128], lsq[128];
    int tid = threadIdx.x;
    if (tid < 128) { lsum[tid] = 0.f; lsq[tid] = 0.f; }
    __syncthreads();

    int wave = tid >> 6, lane = tid & 63;
    int m = lane & 15, quad = lane >> 4;
    long waveBase = (long)blockIdx.x * 128 + wave * 32;

    long row[2]; bool ok[2]; int seg[2];
    #pragma unroll
    for (int t = 0; t < 2; ++t) {
        long r = waveBase + t * 16 + m;
        ok[t]  = (r < N);
        row[t] = ok[t] ? r : (long)N - 1;
        seg[t] = batch[row[t]];               // EARLY issue
    }

    bf16x8 a[2][4];
    #pragma unroll
    for (int t = 0; t < 2; ++t) {
        #pragma unroll
        for (int kb = 0; kb < 4; ++kb)
            a[t][kb] = *(const bf16x8*)(x1 + (size_t)row[t] * 128 + kb * 32 + quad * 8);
    }

    f32x4 acc[2][8];
    #pragma unroll
    for (int t = 0; t < 2; ++t)
        #pragma unroll
        for (int nt = 0; nt < 8; ++nt) acc[t][nt] = (f32x4){0.f, 0.f, 0.f, 0.f};

    #pragma unroll
    for (int nt = 0; nt < 8; ++nt) {
        #pragma unroll
        for (int kb = 0; kb < 4; ++kb) {
            bf16x8 b = *(const bf16x8*)(W2 + (size_t)(nt * 16 + m) * 128 + kb * 32 + quad * 8);
            acc[0][nt] = __builtin_amdgcn_mfma_f32_16x16x32_bf16(b, a[0][kb], acc[0][nt], 0, 0, 0);
            acc[1][nt] = __builtin_amdgcn_mfma_f32_16x16x32_bf16(b, a[1][kb], acc[1][nt], 0, 0, 0);
        }
    }

    // epilogue: per row-tile t, lane owns row row[t]
    #pragma unroll
    for (int t = 0; t < 2; ++t) {
        const float* crow = c2p + (size_t)seg[t] * 128;
        #pragma unroll
        for (int nt = 0; nt < 8; ++nt) {
            float4 c = *(const float4*)(crow + nt * 16 + quad * 4);
            f32x4 v;
            v[0] = acc[t][nt][0] + c.x;
            v[1] = acc[t][nt][1] + c.y;
            v[2] = acc[t][nt][2] + c.z;
            v[3] = acc[t][nt][3] + c.w;
            if (!ok[t]) v = (f32x4){0.f, 0.f, 0.f, 0.f};
            acc[t][nt] = v;            // reuse as BN source (zeroed when invalid)
            if (ok[t]) {
                if (mode) {
                    us4 o;
                    o[0] = f2bf(v[0]); o[1] = f2bf(v[1]); o[2] = f2bf(v[2]); o[3] = f2bf(v[3]);
                    *(us4*)(x2b + (size_t)row[t] * 128 + nt * 16 + quad * 4) = o;
                } else {
                    *(float4*)(x2f + (size_t)row[t] * 128 + nt * 16 + quad * 4) =
                        (float4){v[0], v[1], v[2], v[3]};
                }
            }
        }
    }

    // BN partials: reduce sum & sq across the 16 m-lanes per feature
    #pragma unroll
    for (int nt = 0; nt < 8; ++nt) {
        #pragma unroll
        for (int r = 0; r < 4; ++r) {
            float s = acc[0][nt][r] + acc[1][nt][r];
            float q = acc[0][nt][r] * acc[0][nt][r] + acc[1][nt][r] * acc[1][nt][r];
            s += __shfl_xor(s, 1); s += __shfl_xor(s, 2);
            s += __shfl_xor(s, 4); s += __shfl_xor(s, 8);
            q += __shfl_xor(q, 1); q += __shfl_xor(q, 2);
            q += __shfl_xor(q, 4); q += __shfl_xor(q, 8);
            if (m == 0) {
                int f = nt * 16 + quad * 4 + r;
                atomicAdd(&lsum[f], s);
                atomicAdd(&lsq[f], q);
            }
        }
    }
    __syncthreads();
    if (tid < 128) {
        int rep = (int)(blockIdx.x & (NREP - 1));
        atomicAdd(&bnp[rep * 256 + tid],       lsum[tid]);
        atomicAdd(&bnp[rep * 256 + 128 + tid], lsq[tid]);
    }
}

// ---------------- K8: BN finalize -> scale/shift -------------------------------
__global__ void k_bnfin(const float* __restrict__ bnp, const float* __restrict__ bn_g,
                        const float* __restrict__ bn_b, float* __restrict__ bnscale,
                        float* __restrict__ bnshift, int N) {
    int t = threadIdx.x;   // 128
    float s = 0.f, q = 0.f;
    for (int rep = 0; rep < NREP; ++rep) {
        s += bnp[rep * 256 + t];
        q += bnp[rep * 256 + 128 + t];
    }
    float invN = 1.f / (float)N;
    float mu  = s * invN;
    float var = fmaxf(q * invN - mu * mu, 0.f);
    float sc  = bn_g[t] * rsqrtf(var + 1e-5f);
    bnscale[t] = sc;
    bnshift[t] = bn_b[t] - mu * sc;
}

// ---------------- K9: out = x + x2*scale + shift -------------------------------
__global__ void k_final(const float* __restrict__ x, const unsigned short* __restrict__ x2b,
                        const float* __restrict__ x2f, int mode,
                        const float* __restrict__ bnscale, const float* __restrict__ bnshift,
                        float* __restrict__ out, long nThreads) {
    long i = (long)blockIdx.x * blockDim.x + threadIdx.x;
    if (i >= nThreads) return;
    long base = i * 8;
    int n0 = (int)(base & 127);
    float4 sc0 = *(const float4*)(bnscale + n0);
    float4 sc1 = *(const float4*)(bnscale + n0 + 4);
    float4 sh0 = *(const float4*)(bnshift + n0);
    float4 sh1 = *(const float4*)(bnshift + n0 + 4);
    float4 xa = *(const float4*)(x + base);
    float4 xb = *(const float4*)(x + base + 4);
    float v[8];
    if (mode) {
        us8 u = *(const us8*)(x2b + base);
        #pragma unroll
        for (int j = 0; j < 8; ++j) v[j] = bf2f(u[j]);
    } else {
        float4 va = *(const float4*)(x2f + base);
        float4 vb = *(const float4*)(x2f + base + 4);
        v[0] = va.x; v[1] = va.y; v[2] = va.z; v[3] = va.w;
        v[4] = vb.x; v[5] = vb.y; v[6] = vb.z; v[7] = vb.w;
    }
    float4 oa, ob;
    oa.x = xa.x + v[0] * sc0.x + sh0.x;
    oa.y = xa.y + v[1] * sc0.y + sh0.y;
    oa.z = xa.z + v[2] * sc0.z + sh0.z;
    oa.w = xa.w + v[3] * sc0.w + sh0.w;
    ob.x = xb.x + v[4] * sc1.x + sh1.x;
    ob.y = xb.y + v[5] * sc1.y + sh1.y;
    ob.z = xb.z + v[6] * sc1.z + sh1.z;
    ob.w = xb.w + v[7] * sc1.w + sh1.w;
    *(float4*)(out + base)     = oa;
    *(float4*)(out + base + 4) = ob;
}

extern "C" void kernel_launch(void* const* d_in, const int* in_sizes, int n_in,
                              void* d_out, int out_size, void* d_ws, size_t ws_size,
                              hipStream_t stream) {
    const float* x    = (const float*)d_in[0];
    const int*   bat  = (const int*)  d_in[1];
    const float* pers = (const float*)d_in[2];
    const float* g1w  = (const float*)d_in[3];
    const float* g1b  = (const float*)d_in[4];
    const float* l1w  = (const float*)d_in[5];
    const float* g2w  = (const float*)d_in[6];
    const float* g2b  = (const float*)d_in[7];
    const float* l2w  = (const float*)d_in[8];
    const float* bng  = (const float*)d_in[9];
    const float* bnb  = (const float*)d_in[10];
    int N = in_sizes[1];                 // 500000
    float* out = (float*)d_out;

    // ws layout: zeroed region first (sum2 + bnp only)
    char* ws = (char*)d_ws;
    float* sum2 = (float*)(ws + 0);                       // 2048*128*4 = 1048576
    float* bnp  = (float*)(ws + 1048576);                 // 32*256*4   = 32768
    size_t zero_bytes = 1081344;
    int*   start = (int*)(ws + 1081344);                  // 2049*4 -> pad 8704
    float* cnt  = (float*)(ws + 1090048);                 // 2048*4     = 8192
    float* sum1 = (float*)(ws + 1098240);                 // 2048*144*4 = 1179648
    float* c1p  = (float*)(ws + 2277888);                 // 1048576
    float* c2p  = (float*)(ws + 3326464);                 // 1048576
    unsigned short* W1 = (unsigned short*)(ws + 4375040); // 128*160*2 = 40960
    unsigned short* W2 = (unsigned short*)(ws + 4416000); // 128*128*2 = 32768
    float* bnscale = (float*)(ws + 4448768);              // 512
    float* bnshift = (float*)(ws + 4449280);              // 512
    unsigned short* x1 = (unsigned short*)(ws + 4449792); // N*128*2 = 128000000
    unsigned short* x2b = (unsigned short*)(ws + 132449792); // N*128*2 = 128000000
    size_t need_bf16 = 132449792 + (size_t)N * 128 * 2;
    int mode = (ws_size >= need_bf16) ? 1 : 0;

    hipMemsetAsync(ws, 0, zero_bytes, stream);

    int gridRows128 = (N + 127) / 128;

    k_bounds<<<(NGRAPHS + 256) / 256 + 1, 256, 0, stream>>>(bat, start, N);
    k_prep <<<128, 192, 0, stream>>>(g1w, g2w, W1, W2);
    k_seg1 <<<NGRAPHS, 256, 0, stream>>>(x, pers, start, sum1, cnt, N);
    k_corr <<<NGRAPHS, 128, 0, stream>>>(sum1, cnt, l1w, g1b, c1p, K1DIM);
    k_gemm1<<<gridRows128, 256, 0, stream>>>(x, pers, bat, W1, c1p, x1, sum2, N);
    k_corr <<<NGRAPHS, 128, 0, stream>>>(sum2, cnt, l2w, g2b, c2p, 128);
    k_gemm2<<<gridRows128, 256, 0, stream>>>(x1, bat, W2, c2p, out, x2b, mode, bnp, N);
    k_bnfin<<<1, 128, 0, stream>>>(bnp, bng, bnb, bnscale, bnshift, N);
    long nThreads = ((long)N * 128) / 8;
    k_final<<<(int)((nThreads + 255) / 256), 256, 0, stream>>>(x, x2b, out, mode,
                                                               bnscale, bnshift, out, nThreads);
}